// Round 1
// baseline (1623.642 us; speedup 1.0000x reference)
//
#include <hip/hip_runtime.h>
#include <math.h>

#define HEADS 16
#define HD 64
#define EMB 1024
#define BATCH 4
#define SEQ 2048

// ---------------------------------------------------------------------------
// Kernel A: per-head linear projections.  x:[B,L,H,64] @ W^T[64,64] + b
// Treated as GEMM M=131072, N=64, K=64 (one z-slice per matrix q/k/v).
// Output layout head-major: [B,H,L,64] for coalesced attention access.
// ---------------------------------------------------------------------------
__global__ __launch_bounds__(256) void proj_kernel(
    const float* __restrict__ x_q, const float* __restrict__ x_k, const float* __restrict__ x_v,
    const float* __restrict__ Wq, const float* __restrict__ bq,
    const float* __restrict__ Wk, const float* __restrict__ bk,
    const float* __restrict__ Wv, const float* __restrict__ bv,
    float* __restrict__ qp, float* __restrict__ kp, float* __restrict__ vp)
{
    __shared__ float Xs[64][68];   // Xs[d][m]  (transposed, pad 68 keeps 16B align)
    __shared__ float Ws[64][68];   // Ws[d][e]

    const int t = threadIdx.x;
    const int mat = blockIdx.y;
    const float* __restrict__ X    = (mat == 0) ? x_q : (mat == 1) ? x_k : x_v;
    const float* __restrict__ W    = (mat == 0) ? Wq  : (mat == 1) ? Wk  : Wv;
    const float* __restrict__ bias = (mat == 0) ? bq  : (mat == 1) ? bk  : bv;
    float* __restrict__ dst        = (mat == 0) ? qp  : (mat == 1) ? kp  : vp;

    const long row0 = (long)blockIdx.x * 64;

    #pragma unroll
    for (int i = 0; i < 4; ++i) {
        int c    = t + i * 256;        // float4 chunk id, 0..1023
        int m    = c >> 4;             // row within tile
        int dblk = (c & 15) * 4;       // k-offset
        float4 xv = *(const float4*)(X + (row0 + m) * 64 + dblk);
        Xs[dblk + 0][m] = xv.x; Xs[dblk + 1][m] = xv.y;
        Xs[dblk + 2][m] = xv.z; Xs[dblk + 3][m] = xv.w;
        float4 wv = *(const float4*)(W + m * 64 + dblk);
        Ws[dblk + 0][m] = wv.x; Ws[dblk + 1][m] = wv.y;
        Ws[dblk + 2][m] = wv.z; Ws[dblk + 3][m] = wv.w;
    }
    __syncthreads();

    const int mi = (t & 15) * 4;
    const int ei = (t >> 4) * 4;
    float acc[4][4];
    #pragma unroll
    for (int i = 0; i < 4; ++i)
        #pragma unroll
        for (int j = 0; j < 4; ++j) acc[i][j] = 0.f;

    #pragma unroll 8
    for (int d = 0; d < 64; ++d) {
        float4 a = *(const float4*)&Xs[d][mi];
        float4 w = *(const float4*)&Ws[d][ei];
        const float av[4] = {a.x, a.y, a.z, a.w};
        const float wv[4] = {w.x, w.y, w.z, w.w};
        #pragma unroll
        for (int i = 0; i < 4; ++i)
            #pragma unroll
            for (int j = 0; j < 4; ++j)
                acc[i][j] = fmaf(av[i], wv[j], acc[i][j]);
    }

    const float b0 = bias[ei + 0], b1 = bias[ei + 1], b2 = bias[ei + 2], b3 = bias[ei + 3];
    #pragma unroll
    for (int i = 0; i < 4; ++i) {
        long gr = row0 + mi + i;             // global row = (b*L + l)*H + h
        int b = (int)(gr >> 15);             // / (SEQ*HEADS)
        int l = (int)(gr >> 4) & (SEQ - 1);
        int h = (int)gr & (HEADS - 1);
        float4 o;
        o.x = acc[i][0] + b0; o.y = acc[i][1] + b1;
        o.z = acc[i][2] + b2; o.w = acc[i][3] + b3;
        *(float4*)(dst + ((long)(b * HEADS + h) * SEQ + l) * 64 + ei) = o;
    }
}

// ---------------------------------------------------------------------------
// Kernel B: attention for one (b,h), 128 query rows per block.
// scores = floor((q.k  masked)/8); online softmax; acc += p*v.
// Thread layout: rq = t>>2 owns rows (q0+rq) and (q0+64+rq); sub = t&3 owns
// dims [sub*16, sub*16+16).  Score reduced across the 4 sub lanes via shfl.
// ---------------------------------------------------------------------------
__global__ __launch_bounds__(256) void attn_kernel(
    const float* __restrict__ qp, const float* __restrict__ kp,
    const float* __restrict__ vp, const int* __restrict__ mask,
    float* __restrict__ ao)
{
    __shared__ float Ks[64][68];
    __shared__ float Vs[64][68];
    __shared__ float msf[64];

    const int t  = threadIdx.x;
    const int bh = blockIdx.y;          // b*HEADS + h
    const int b  = bh >> 4;
    const int h  = bh & 15;
    const int q0 = blockIdx.x * 128;
    const int rq  = t >> 2;
    const int sub = t & 3;
    const long base = (long)bh * SEQ * 64;

    float qA[16], qB[16];
    {
        const float* qrA = qp + base + (long)(q0 + rq) * 64 + sub * 16;
        const float* qrB = qp + base + (long)(q0 + 64 + rq) * 64 + sub * 16;
        #pragma unroll
        for (int i = 0; i < 4; ++i) {
            float4 a = *(const float4*)(qrA + 4 * i);
            qA[4*i+0] = a.x; qA[4*i+1] = a.y; qA[4*i+2] = a.z; qA[4*i+3] = a.w;
            float4 c = *(const float4*)(qrB + 4 * i);
            qB[4*i+0] = c.x; qB[4*i+1] = c.y; qB[4*i+2] = c.z; qB[4*i+3] = c.w;
        }
    }

    float accA[16], accB[16];
    #pragma unroll
    for (int j = 0; j < 16; ++j) { accA[j] = 0.f; accB[j] = 0.f; }
    float mA = -INFINITY, mB = -INFINITY, lA = 0.f, lB = 0.f;

    for (int kt = 0; kt < SEQ; kt += 64) {
        __syncthreads();
        #pragma unroll
        for (int i = 0; i < 4; ++i) {
            int c    = t + i * 256;
            int kk   = c >> 4;
            int dblk = (c & 15) * 4;
            float4 kv = *(const float4*)(kp + base + (long)(kt + kk) * 64 + dblk);
            *(float4*)&Ks[kk][dblk] = kv;
            float4 vv = *(const float4*)(vp + base + (long)(kt + kk) * 64 + dblk);
            *(float4*)&Vs[kk][dblk] = vv;
        }
        if (t < 64) msf[t] = (mask[b * SEQ + kt + t] == 0) ? -1e20f : 0.0f;
        __syncthreads();

        #pragma unroll 2
        for (int k = 0; k < 64; ++k) {
            float kvr[16];
            const float4* kr = (const float4*)&Ks[k][sub * 16];
            *(float4*)&kvr[0]  = kr[0]; *(float4*)&kvr[4]  = kr[1];
            *(float4*)&kvr[8]  = kr[2]; *(float4*)&kvr[12] = kr[3];

            float pA = 0.f, pB = 0.f;
            #pragma unroll
            for (int j = 0; j < 16; ++j) {
                pA = fmaf(qA[j], kvr[j], pA);
                pB = fmaf(qB[j], kvr[j], pB);
            }
            // reduce across the 4 sub lanes (bitwise-identical on all 4)
            pA += __shfl_xor(pA, 1); pA += __shfl_xor(pA, 2);
            pB += __shfl_xor(pB, 1); pB += __shfl_xor(pB, 2);

            const float mk = msf[k];
            float sA = floorf((pA + mk) * 0.125f);
            float sB = floorf((pB + mk) * 0.125f);

            if (sA > mA) {
                float sc = __expf(mA - sA); mA = sA; lA *= sc;
                #pragma unroll
                for (int j = 0; j < 16; ++j) accA[j] *= sc;
            }
            float eA = __expf(sA - mA); lA += eA;
            if (sB > mB) {
                float sc = __expf(mB - sB); mB = sB; lB *= sc;
                #pragma unroll
                for (int j = 0; j < 16; ++j) accB[j] *= sc;
            }
            float eB = __expf(sB - mB); lB += eB;

            float vvr[16];
            const float4* vr = (const float4*)&Vs[k][sub * 16];
            *(float4*)&vvr[0]  = vr[0]; *(float4*)&vvr[4]  = vr[1];
            *(float4*)&vvr[8]  = vr[2]; *(float4*)&vvr[12] = vr[3];
            #pragma unroll
            for (int j = 0; j < 16; ++j) {
                accA[j] = fmaf(eA, vvr[j], accA[j]);
                accB[j] = fmaf(eB, vvr[j], accB[j]);
            }
        }
    }

    const float rA = 1.0f / lA, rB = 1.0f / lB;
    float* oA = ao + (long)(b * SEQ + q0 + rq) * EMB + h * 64 + sub * 16;
    float* oB = ao + (long)(b * SEQ + q0 + 64 + rq) * EMB + h * 64 + sub * 16;
    #pragma unroll
    for (int i = 0; i < 4; ++i) {
        float4 o;
        o.x = accA[4*i+0] * rA; o.y = accA[4*i+1] * rA;
        o.z = accA[4*i+2] * rA; o.w = accA[4*i+3] * rA;
        *(float4*)(oA + 4 * i) = o;
        float4 p;
        p.x = accB[4*i+0] * rB; p.y = accB[4*i+1] * rB;
        p.z = accB[4*i+2] * rB; p.w = accB[4*i+3] * rB;
        *(float4*)(oB + 4 * i) = p;
    }
}

// ---------------------------------------------------------------------------
// Kernel C: out = ao[8192,1024] @ Wfc^T[1024,1024] + bfc.  64x64 tile / block.
// ---------------------------------------------------------------------------
__global__ __launch_bounds__(256) void fc_kernel(
    const float* __restrict__ A, const float* __restrict__ W,
    const float* __restrict__ bias, float* __restrict__ out)
{
    __shared__ float As[32][68];   // As[k][m]
    __shared__ float Bs[32][68];   // Bs[k][n]

    const int t  = threadIdx.x;
    const int m0 = blockIdx.x * 64;
    const int n0 = blockIdx.y * 64;
    const int mi = (t & 15) * 4;
    const int ni = (t >> 4) * 4;

    float acc[4][4];
    #pragma unroll
    for (int i = 0; i < 4; ++i)
        #pragma unroll
        for (int j = 0; j < 4; ++j) acc[i][j] = 0.f;

    for (int k0 = 0; k0 < 1024; k0 += 32) {
        __syncthreads();
        #pragma unroll
        for (int i = 0; i < 2; ++i) {
            int c  = t + i * 256;          // 0..511 float4 chunks
            int m  = c >> 3;
            int kb = (c & 7) * 4;
            float4 av = *(const float4*)(A + (long)(m0 + m) * 1024 + k0 + kb);
            As[kb + 0][m] = av.x; As[kb + 1][m] = av.y;
            As[kb + 2][m] = av.z; As[kb + 3][m] = av.w;
            float4 wv = *(const float4*)(W + (long)(n0 + m) * 1024 + k0 + kb);
            Bs[kb + 0][m] = wv.x; Bs[kb + 1][m] = wv.y;
            Bs[kb + 2][m] = wv.z; Bs[kb + 3][m] = wv.w;
        }
        __syncthreads();
        #pragma unroll 8
        for (int k = 0; k < 32; ++k) {
            float4 a = *(const float4*)&As[k][mi];
            float4 w = *(const float4*)&Bs[k][ni];
            const float av[4] = {a.x, a.y, a.z, a.w};
            const float wv[4] = {w.x, w.y, w.z, w.w};
            #pragma unroll
            for (int i = 0; i < 4; ++i)
                #pragma unroll
                for (int j = 0; j < 4; ++j)
                    acc[i][j] = fmaf(av[i], wv[j], acc[i][j]);
        }
    }

    const float b0 = bias[n0 + ni + 0], b1 = bias[n0 + ni + 1];
    const float b2 = bias[n0 + ni + 2], b3 = bias[n0 + ni + 3];
    #pragma unroll
    for (int i = 0; i < 4; ++i) {
        float4 o;
        o.x = acc[i][0] + b0; o.y = acc[i][1] + b1;
        o.z = acc[i][2] + b2; o.w = acc[i][3] + b3;
        *(float4*)(out + (long)(m0 + mi + i) * 1024 + n0 + ni) = o;
    }
}

// ---------------------------------------------------------------------------
extern "C" void kernel_launch(void* const* d_in, const int* in_sizes, int n_in,
                              void* d_out, int out_size, void* d_ws, size_t ws_size,
                              hipStream_t stream)
{
    const float* q    = (const float*)d_in[0];
    const float* k    = (const float*)d_in[1];
    const float* v    = (const float*)d_in[2];
    const int*   mask = (const int*)  d_in[3];
    const float* Wq   = (const float*)d_in[4];
    const float* bq   = (const float*)d_in[5];
    const float* Wk   = (const float*)d_in[6];
    const float* bk   = (const float*)d_in[7];
    const float* Wv   = (const float*)d_in[8];
    const float* bv   = (const float*)d_in[9];
    const float* Wfc  = (const float*)d_in[10];
    const float* bfc  = (const float*)d_in[11];
    float* out = (float*)d_out;

    const long NP = (long)BATCH * HEADS * SEQ * 64;   // 8,388,608 floats
    float* ws = (float*)d_ws;
    float* qp = ws;
    float* kp = ws + NP;
    float* vp = ws + 2 * NP;
    float* ao = ws + 3 * NP;   // [B*L, EMB]

    dim3 gA((BATCH * SEQ * HEADS) / 64, 3);
    proj_kernel<<<gA, 256, 0, stream>>>(q, k, v, Wq, bq, Wk, bk, Wv, bv, qp, kp, vp);

    dim3 gB(SEQ / 128, BATCH * HEADS);
    attn_kernel<<<gB, 256, 0, stream>>>(qp, kp, vp, mask, ao);

    dim3 gC((BATCH * SEQ) / 64, EMB / 64);
    fc_kernel<<<gC, 256, 0, stream>>>(ao, Wfc, bfc, out);
}

// Round 2
// 523.073 us; speedup vs baseline: 3.1040x; 3.1040x over previous
//
#include <hip/hip_runtime.h>
#include <math.h>

#define HEADS 16
#define EMB 1024
#define BATCH 4
#define SEQ 2048

typedef __bf16 bf16_t;
typedef __bf16 bf16x4 __attribute__((ext_vector_type(4)));
typedef __bf16 bf16x8 __attribute__((ext_vector_type(8)));
typedef float f32x4 __attribute__((ext_vector_type(4)));
typedef float f32x16 __attribute__((ext_vector_type(16)));
typedef unsigned int u32x4 __attribute__((ext_vector_type(4)));

__device__ __forceinline__ f32x16 mfma32(bf16x8 a, bf16x8 b, f32x16 c) {
    return __builtin_amdgcn_mfma_f32_32x32x16_bf16(a, b, c, 0, 0, 0);
}

__device__ __forceinline__ unsigned cvtpk(float lo, float hi) {
    unsigned r;
    asm("v_cvt_pk_bf16_f32 %0, %1, %2" : "=v"(r) : "v"(lo), "v"(hi));
    return r;
}

__device__ __forceinline__ void plswap(unsigned &a, unsigned &b) {
    asm volatile("v_permlane32_swap_b32 %0, %1" : "+v"(a), "+v"(b));
}

// ---------------------------------------------------------------------------
// Mask -> multiplier (1.0 keep, 0.0 drop)
// ---------------------------------------------------------------------------
__global__ void maskf_kernel(const int* __restrict__ mask, float* __restrict__ mf, int n) {
    int i = blockIdx.x * 256 + threadIdx.x;
    if (i < n) mf[i] = mask[i] ? 1.0f : 0.0f;
}

// Wfc f32 -> bf16
__global__ void wconv_kernel(const float* __restrict__ w, bf16_t* __restrict__ wb, int n) {
    int i = (blockIdx.x * 256 + threadIdx.x) * 4;
    if (i < n) {
        float4 f = *(const float4*)(w + i);
        bf16x4 o;
        o[0] = (bf16_t)f.x; o[1] = (bf16_t)f.y; o[2] = (bf16_t)f.z; o[3] = (bf16_t)f.w;
        *(bf16x4*)(wb + i) = o;
    }
}

// ---------------------------------------------------------------------------
// Projections: per 64-row tile of ONE (b,h).  Writes:
//   q_hi/q_lo, k_hi/k_lo : [bh][l][64] bf16 (hi/lo split of fp32 result)
//   vt                   : [bh][64][SEQ] bf16 (transposed)
// ---------------------------------------------------------------------------
__global__ __launch_bounds__(256) void proj_kernel(
    const float* __restrict__ xq, const float* __restrict__ xk, const float* __restrict__ xv,
    const float* __restrict__ Wq, const float* __restrict__ bq,
    const float* __restrict__ Wk, const float* __restrict__ bk,
    const float* __restrict__ Wv, const float* __restrict__ bv,
    bf16_t* __restrict__ qh, bf16_t* __restrict__ ql,
    bf16_t* __restrict__ khp, bf16_t* __restrict__ klp,
    bf16_t* __restrict__ vt)
{
    __shared__ float Xs[64][68];   // Xs[d][l]
    __shared__ float Ws[64][68];   // Ws[d][e]

    const int t   = threadIdx.x;
    const int mat = blockIdx.y;
    const int bh  = blockIdx.x >> 5;
    const int l0  = (blockIdx.x & 31) * 64;
    const int b   = bh >> 4;
    const int hh  = bh & 15;

    const float* __restrict__ X    = (mat == 0) ? xq : (mat == 1) ? xk : xv;
    const float* __restrict__ W    = (mat == 0) ? Wq : (mat == 1) ? Wk : Wv;
    const float* __restrict__ bias = (mat == 0) ? bq : (mat == 1) ? bk : bv;

    #pragma unroll
    for (int i = 0; i < 4; ++i) {
        int c    = t + i * 256;
        int l    = c >> 4;
        int dblk = (c & 15) * 4;
        float4 xv4 = *(const float4*)(X + ((long)(b * SEQ + l0 + l)) * EMB + hh * 64 + dblk);
        Xs[dblk + 0][l] = xv4.x; Xs[dblk + 1][l] = xv4.y;
        Xs[dblk + 2][l] = xv4.z; Xs[dblk + 3][l] = xv4.w;
        float4 wv4 = *(const float4*)(W + l * 64 + dblk);     // l plays 'e' here
        Ws[dblk + 0][l] = wv4.x; Ws[dblk + 1][l] = wv4.y;
        Ws[dblk + 2][l] = wv4.z; Ws[dblk + 3][l] = wv4.w;
    }
    __syncthreads();

    const int mi = (t & 15) * 4;   // l within tile
    const int ei = (t >> 4) * 4;   // output dim
    float acc[4][4];
    #pragma unroll
    for (int i = 0; i < 4; ++i)
        #pragma unroll
        for (int j = 0; j < 4; ++j) acc[i][j] = 0.f;

    #pragma unroll 8
    for (int d = 0; d < 64; ++d) {
        float4 a = *(const float4*)&Xs[d][mi];
        float4 w = *(const float4*)&Ws[d][ei];
        const float av[4] = {a.x, a.y, a.z, a.w};
        const float wv[4] = {w.x, w.y, w.z, w.w};
        #pragma unroll
        for (int i = 0; i < 4; ++i)
            #pragma unroll
            for (int j = 0; j < 4; ++j)
                acc[i][j] = fmaf(av[i], wv[j], acc[i][j]);
    }

    const float bb[4] = {bias[ei + 0], bias[ei + 1], bias[ei + 2], bias[ei + 3]};

    if (mat < 2) {
        bf16_t* dh = (mat == 0) ? qh : khp;
        bf16_t* dl = (mat == 0) ? ql : klp;
        #pragma unroll
        for (int i = 0; i < 4; ++i) {
            long addr = ((long)(bh * SEQ + l0 + mi + i)) * 64 + ei;
            bf16x4 h4, l4;
            #pragma unroll
            for (int j = 0; j < 4; ++j) {
                float y = acc[i][j] + bb[j];
                bf16_t hi = (bf16_t)y;
                h4[j] = hi;
                l4[j] = (bf16_t)(y - (float)hi);
            }
            *(bf16x4*)(dh + addr) = h4;
            *(bf16x4*)(dl + addr) = l4;
        }
    } else {
        #pragma unroll
        for (int j = 0; j < 4; ++j) {
            int d = ei + j;
            bf16x4 v4;
            #pragma unroll
            for (int i = 0; i < 4; ++i) v4[i] = (bf16_t)(acc[i][j] + bb[j]);
            *(bf16x4*)(vt + ((long)(bh * 64 + d)) * SEQ + l0 + mi) = v4;
        }
    }
}

// ---------------------------------------------------------------------------
// Attention.  1 block = 4 independent waves; wave owns 32 q-rows of one (b,h).
// Swapped QK^T: S^T = mfma(K, Q) -> q-row in lane (col), key in reg (crow).
// 3-term hi/lo emulation for fp32-accurate scores (floor-flip safety).
// p = exp(floor(s/8)) * maskmul  (no max tracking: s is a small int).
// P -> A-fragment via cvt_pk + v_permlane32_swap; PV from V^T 16B loads.
// ---------------------------------------------------------------------------
__global__ __launch_bounds__(256) void attn_kernel(
    const bf16_t* __restrict__ qh, const bf16_t* __restrict__ ql,
    const bf16_t* __restrict__ kh, const bf16_t* __restrict__ kl,
    const bf16_t* __restrict__ vt, const float* __restrict__ mf,
    bf16_t* __restrict__ ao)
{
    // XCD-aware swizzle: 16 q-blocks of one bh land on one XCD (round-robin g&7)
    const int g   = blockIdx.x;
    const int xcd = g & 7;
    const int seq = g >> 3;
    const int bh  = ((seq >> 4) << 3) + xcd;
    const int qb  = seq & 15;
    const int b   = bh >> 4;
    const int hh  = bh & 15;

    const int lane = threadIdx.x & 63;
    const int wave = threadIdx.x >> 6;
    const int col  = lane & 31;
    const int hf   = lane >> 5;

    const int q0 = qb * 128 + wave * 32;

    // Q fragments (B-operand): lane holds Q[q0+col][16c + 8*hf .. +7]
    const long qoff = ((long)(bh * SEQ + q0 + col)) * 64 + hf * 8;
    bf16x8 qfh[4], qfl[4];
    #pragma unroll
    for (int c = 0; c < 4; ++c) {
        qfh[c] = *(const bf16x8*)(qh + qoff + 16 * c);
        qfl[c] = *(const bf16x8*)(ql + qoff + 16 * c);
    }

    f32x16 o0 = {};
    f32x16 o1 = {};
    float lacc = 0.f;
    const float* mrow = mf + b * SEQ;

    for (int kt = 0; kt < SEQ; kt += 32) {
        // K fragments (A-operand): lane holds K[kt+col][16c + 8*hf .. +7]
        const long koff = ((long)(bh * SEQ + kt + col)) * 64 + hf * 8;
        f32x16 s = {};
        #pragma unroll
        for (int c = 0; c < 4; ++c) {
            bf16x8 kfh = *(const bf16x8*)(kh + koff + 16 * c);
            bf16x8 kfl = *(const bf16x8*)(kl + koff + 16 * c);
            s = mfma32(kfh, qfh[c], s);
            s = mfma32(kfh, qfl[c], s);
            s = mfma32(kfl, qfh[c], s);
        }

        // mask multipliers: reg r covers key kt + (r&3) + 8*(r>>2) + 4*hf
        f32x4 mm[4];
        #pragma unroll
        for (int gi = 0; gi < 4; ++gi)
            mm[gi] = *(const f32x4*)(mrow + kt + 8 * gi + 4 * hf);

        float p[16];
        #pragma unroll
        for (int r = 0; r < 16; ++r) {
            float sv = floorf(s[r] * 0.125f);
            p[r] = __expf(sv) * mm[r >> 2][r & 3];
            lacc += p[r];
        }

        // pack P into PV A-fragments (keys chunk0: 0..15, chunk1: 16..31)
        unsigned w0 = cvtpk(p[0], p[1]),   w1 = cvtpk(p[2], p[3]);
        unsigned w2 = cvtpk(p[4], p[5]),   w3 = cvtpk(p[6], p[7]);
        plswap(w0, w2); plswap(w1, w3);
        unsigned w4 = cvtpk(p[8], p[9]),   w5 = cvtpk(p[10], p[11]);
        unsigned w6 = cvtpk(p[12], p[13]), w7 = cvtpk(p[14], p[15]);
        plswap(w4, w6); plswap(w5, w7);
        u32x4 pa0u = {w0, w1, w2, w3};
        u32x4 pa1u = {w4, w5, w6, w7};
        bf16x8 pa0 = __builtin_bit_cast(bf16x8, pa0u);
        bf16x8 pa1 = __builtin_bit_cast(bf16x8, pa1u);

        // V fragments (B-operand) from V^T: lane holds V[key][dim=nt*32+col]
        const long vbase = ((long)(bh * 64)) * SEQ + kt + hf * 8;
        bf16x8 v00 = *(const bf16x8*)(vt + vbase + (long)col * SEQ);
        bf16x8 v01 = *(const bf16x8*)(vt + vbase + (long)col * SEQ + 16);
        bf16x8 v10 = *(const bf16x8*)(vt + vbase + (long)(col + 32) * SEQ);
        bf16x8 v11 = *(const bf16x8*)(vt + vbase + (long)(col + 32) * SEQ + 16);

        o0 = mfma32(pa0, v00, o0);
        o0 = mfma32(pa1, v01, o0);
        o1 = mfma32(pa0, v10, o1);
        o1 = mfma32(pa1, v11, o1);
    }

    // row sums: lane holds partial over its half's key pattern
    float ltot = lacc + __shfl_xor(lacc, 32);
    float linv = 1.0f / ltot;

    const long obase = ((long)(b * SEQ + q0)) * EMB + hh * 64;
    #pragma unroll
    for (int r = 0; r < 16; ++r) {
        int row = (r & 3) + ((r >> 2) << 3) + 4 * hf;   // q-row within 32
        float li = __shfl(linv, row);                   // l lives at lane 'row'
        ao[obase + (long)row * EMB + col]      = (bf16_t)(o0[r] * li);
        ao[obase + (long)row * EMB + col + 32] = (bf16_t)(o1[r] * li);
    }
}

// ---------------------------------------------------------------------------
// FC: out[8192,1024] = ao_bf16 @ Wfc_bf16^T + bfc.  Block = 128x128, 4 waves,
// wave = 64x64 (2x2 32x32 MFMA tiles).  Direct global fragment loads.
// ---------------------------------------------------------------------------
__global__ __launch_bounds__(256) void fc_kernel(
    const bf16_t* __restrict__ A, const bf16_t* __restrict__ W,
    const float* __restrict__ bias, float* __restrict__ out)
{
    const int lane = threadIdx.x & 63;
    const int wave = threadIdx.x >> 6;
    const int col  = lane & 31;
    const int hf   = lane >> 5;
    const int wm   = wave & 1;
    const int wn   = wave >> 1;
    const int m0   = blockIdx.x * 128 + wm * 64;
    const int n0   = blockIdx.y * 128 + wn * 64;

    f32x16 acc[2][2] = {};
    const bf16_t* arow0 = A + (long)(m0 + col) * EMB + hf * 8;
    const bf16_t* arow1 = A + (long)(m0 + 32 + col) * EMB + hf * 8;
    const bf16_t* brow0 = W + (long)(n0 + col) * EMB + hf * 8;
    const bf16_t* brow1 = W + (long)(n0 + 32 + col) * EMB + hf * 8;

    #pragma unroll 2
    for (int k0 = 0; k0 < EMB; k0 += 16) {
        bf16x8 a0 = *(const bf16x8*)(arow0 + k0);
        bf16x8 a1 = *(const bf16x8*)(arow1 + k0);
        bf16x8 b0 = *(const bf16x8*)(brow0 + k0);
        bf16x8 b1 = *(const bf16x8*)(brow1 + k0);
        acc[0][0] = mfma32(a0, b0, acc[0][0]);
        acc[0][1] = mfma32(a0, b1, acc[0][1]);
        acc[1][0] = mfma32(a1, b0, acc[1][0]);
        acc[1][1] = mfma32(a1, b1, acc[1][1]);
    }

    const float b0v = bias[n0 + col];
    const float b1v = bias[n0 + 32 + col];
    #pragma unroll
    for (int mt = 0; mt < 2; ++mt) {
        #pragma unroll
        for (int r = 0; r < 16; ++r) {
            int mrow = m0 + mt * 32 + (r & 3) + ((r >> 2) << 3) + 4 * hf;
            out[(long)mrow * EMB + n0 + col]      = acc[mt][0][r] + b0v;
            out[(long)mrow * EMB + n0 + 32 + col] = acc[mt][1][r] + b1v;
        }
    }
}

// ---------------------------------------------------------------------------
extern "C" void kernel_launch(void* const* d_in, const int* in_sizes, int n_in,
                              void* d_out, int out_size, void* d_ws, size_t ws_size,
                              hipStream_t stream)
{
    const float* q    = (const float*)d_in[0];
    const float* k    = (const float*)d_in[1];
    const float* v    = (const float*)d_in[2];
    const int*   mask = (const int*)  d_in[3];
    const float* Wq   = (const float*)d_in[4];
    const float* bq   = (const float*)d_in[5];
    const float* Wk   = (const float*)d_in[6];
    const float* bk   = (const float*)d_in[7];
    const float* Wv   = (const float*)d_in[8];
    const float* bv   = (const float*)d_in[9];
    const float* Wfc  = (const float*)d_in[10];
    const float* bfc  = (const float*)d_in[11];
    float* out = (float*)d_out;

    const long NP = (long)BATCH * HEADS * SEQ * 64;   // 8,388,608 elems
    bf16_t* qhp = (bf16_t*)d_ws;
    bf16_t* qlp = qhp + NP;
    bf16_t* khp = qlp + NP;
    bf16_t* klp = khp + NP;
    bf16_t* vtp = klp + NP;
    bf16_t* aop = vtp + NP;                 // [B*SEQ][EMB] bf16
    bf16_t* wbp = aop + (long)BATCH * SEQ * EMB;   // [EMB][EMB] bf16
    float*  mfp = (float*)(wbp + (long)EMB * EMB);

    maskf_kernel<<<(BATCH * SEQ + 255) / 256, 256, 0, stream>>>(mask, mfp, BATCH * SEQ);
    wconv_kernel<<<(EMB * EMB / 4) / 256, 256, 0, stream>>>(Wfc, wbp, EMB * EMB);

    dim3 gP(2048, 3);
    proj_kernel<<<gP, 256, 0, stream>>>(q, k, v, Wq, bq, Wk, bk, Wv, bv,
                                        qhp, qlp, khp, klp, vtp);

    attn_kernel<<<1024, 256, 0, stream>>>(qhp, qlp, khp, klp, vtp, mfp, aop);

    dim3 gC(64, 8);
    fc_kernel<<<gC, 256, 0, stream>>>(aop, wbp, bfc, out);
}

// Round 3
// 301.396 us; speedup vs baseline: 5.3871x; 1.7355x over previous
//
#include <hip/hip_runtime.h>
#include <math.h>

#define HEADS 16
#define EMB 1024
#define BATCH 4
#define SEQ 2048

typedef __bf16 bf16_t;
typedef __bf16 bf16x4 __attribute__((ext_vector_type(4)));
typedef __bf16 bf16x8 __attribute__((ext_vector_type(8)));
typedef float f32x4 __attribute__((ext_vector_type(4)));
typedef float f32x16 __attribute__((ext_vector_type(16)));
typedef unsigned int u32x4 __attribute__((ext_vector_type(4)));

__device__ __forceinline__ f32x16 mfma32(bf16x8 a, bf16x8 b, f32x16 c) {
    return __builtin_amdgcn_mfma_f32_32x32x16_bf16(a, b, c, 0, 0, 0);
}

__device__ __forceinline__ unsigned cvtpk(float lo, float hi) {
    unsigned r;
    asm("v_cvt_pk_bf16_f32 %0, %1, %2" : "=v"(r) : "v"(lo), "v"(hi));
    return r;
}

__device__ __forceinline__ void plswap(unsigned &a, unsigned &b) {
    asm volatile("v_permlane32_swap_b32 %0, %1" : "+v"(a), "+v"(b));
}

// Pack 16 per-lane P values (QK^T output layout) into the two PV A-fragments.
__device__ __forceinline__ void pack_p(const float* p, bf16x8& pa0, bf16x8& pa1) {
    unsigned w0 = cvtpk(p[0], p[1]),   w1 = cvtpk(p[2], p[3]);
    unsigned w2 = cvtpk(p[4], p[5]),   w3 = cvtpk(p[6], p[7]);
    plswap(w0, w2); plswap(w1, w3);
    unsigned w4 = cvtpk(p[8], p[9]),   w5 = cvtpk(p[10], p[11]);
    unsigned w6 = cvtpk(p[12], p[13]), w7 = cvtpk(p[14], p[15]);
    plswap(w4, w6); plswap(w5, w7);
    u32x4 ua = {w0, w1, w2, w3};
    u32x4 ub = {w4, w5, w6, w7};
    pa0 = __builtin_bit_cast(bf16x8, ua);
    pa1 = __builtin_bit_cast(bf16x8, ub);
}

// ---------------------------------------------------------------------------
// Mask -> multiplier (1.0 keep, 0.0 drop)
// ---------------------------------------------------------------------------
__global__ void maskf_kernel(const int* __restrict__ mask, float* __restrict__ mf, int n) {
    int i = blockIdx.x * 256 + threadIdx.x;
    if (i < n) mf[i] = mask[i] ? 1.0f : 0.0f;
}

// Wfc f32 -> bf16
__global__ void wconv_kernel(const float* __restrict__ w, bf16_t* __restrict__ wb, int n) {
    int i = (blockIdx.x * 256 + threadIdx.x) * 4;
    if (i < n) {
        float4 f = *(const float4*)(w + i);
        bf16x4 o;
        o[0] = (bf16_t)f.x; o[1] = (bf16_t)f.y; o[2] = (bf16_t)f.z; o[3] = (bf16_t)f.w;
        *(bf16x4*)(wb + i) = o;
    }
}

// ---------------------------------------------------------------------------
// Projections: per 64-row tile of ONE (b,h).  Writes:
//   q_hi/q_lo, k_hi/k_lo : [bh][l][64] bf16 (hi/lo split of fp32 result)
//   vt                   : [bh][64][SEQ] bf16 (transposed)
// ---------------------------------------------------------------------------
__global__ __launch_bounds__(256) void proj_kernel(
    const float* __restrict__ xq, const float* __restrict__ xk, const float* __restrict__ xv,
    const float* __restrict__ Wq, const float* __restrict__ bq,
    const float* __restrict__ Wk, const float* __restrict__ bk,
    const float* __restrict__ Wv, const float* __restrict__ bv,
    bf16_t* __restrict__ qh, bf16_t* __restrict__ ql,
    bf16_t* __restrict__ khp, bf16_t* __restrict__ klp,
    bf16_t* __restrict__ vt)
{
    __shared__ float Xs[64][68];   // Xs[d][l]
    __shared__ float Ws[64][68];   // Ws[d][e]

    const int t   = threadIdx.x;
    const int mat = blockIdx.y;
    const int bh  = blockIdx.x >> 5;
    const int l0  = (blockIdx.x & 31) * 64;
    const int b   = bh >> 4;
    const int hh  = bh & 15;

    const float* __restrict__ X    = (mat == 0) ? xq : (mat == 1) ? xk : xv;
    const float* __restrict__ W    = (mat == 0) ? Wq : (mat == 1) ? Wk : Wv;
    const float* __restrict__ bias = (mat == 0) ? bq : (mat == 1) ? bk : bv;

    #pragma unroll
    for (int i = 0; i < 4; ++i) {
        int c    = t + i * 256;
        int l    = c >> 4;
        int dblk = (c & 15) * 4;
        float4 xv4 = *(const float4*)(X + ((long)(b * SEQ + l0 + l)) * EMB + hh * 64 + dblk);
        Xs[dblk + 0][l] = xv4.x; Xs[dblk + 1][l] = xv4.y;
        Xs[dblk + 2][l] = xv4.z; Xs[dblk + 3][l] = xv4.w;
        float4 wv4 = *(const float4*)(W + l * 64 + dblk);     // l plays 'e' here
        Ws[dblk + 0][l] = wv4.x; Ws[dblk + 1][l] = wv4.y;
        Ws[dblk + 2][l] = wv4.z; Ws[dblk + 3][l] = wv4.w;
    }
    __syncthreads();

    const int mi = (t & 15) * 4;   // l within tile
    const int ei = (t >> 4) * 4;   // output dim
    float acc[4][4];
    #pragma unroll
    for (int i = 0; i < 4; ++i)
        #pragma unroll
        for (int j = 0; j < 4; ++j) acc[i][j] = 0.f;

    #pragma unroll 8
    for (int d = 0; d < 64; ++d) {
        float4 a = *(const float4*)&Xs[d][mi];
        float4 w = *(const float4*)&Ws[d][ei];
        const float av[4] = {a.x, a.y, a.z, a.w};
        const float wv[4] = {w.x, w.y, w.z, w.w};
        #pragma unroll
        for (int i = 0; i < 4; ++i)
            #pragma unroll
            for (int j = 0; j < 4; ++j)
                acc[i][j] = fmaf(av[i], wv[j], acc[i][j]);
    }

    const float bb[4] = {bias[ei + 0], bias[ei + 1], bias[ei + 2], bias[ei + 3]};

    if (mat < 2) {
        bf16_t* dh = (mat == 0) ? qh : khp;
        bf16_t* dl = (mat == 0) ? ql : klp;
        #pragma unroll
        for (int i = 0; i < 4; ++i) {
            long addr = ((long)(bh * SEQ + l0 + mi + i)) * 64 + ei;
            bf16x4 h4, l4;
            #pragma unroll
            for (int j = 0; j < 4; ++j) {
                float y = acc[i][j] + bb[j];
                bf16_t hi = (bf16_t)y;
                h4[j] = hi;
                l4[j] = (bf16_t)(y - (float)hi);
            }
            *(bf16x4*)(dh + addr) = h4;
            *(bf16x4*)(dl + addr) = l4;
        }
    } else {
        #pragma unroll
        for (int j = 0; j < 4; ++j) {
            int d = ei + j;
            bf16x4 v4;
            #pragma unroll
            for (int i = 0; i < 4; ++i) v4[i] = (bf16_t)(acc[i][j] + bb[j]);
            *(bf16x4*)(vt + ((long)(bh * 64 + d)) * SEQ + l0 + mi) = v4;
        }
    }
}

// ---------------------------------------------------------------------------
// Attention.  Block = 4 waves; wave owns 64 q-rows (2 tiles of 32) of one
// (b,h).  Grid = 512.  Swapped QK^T (S^T = mfma(K,Q)), split s-accumulators,
// two independent tile-streams per wave sharing K/V/mask fragments.
// p = exp(floor(s/8)) * maskmul  (no max tracking: s is a tiny int).
// ---------------------------------------------------------------------------
__global__ __launch_bounds__(256, 2) void attn_kernel(
    const bf16_t* __restrict__ qh, const bf16_t* __restrict__ ql,
    const bf16_t* __restrict__ kh, const bf16_t* __restrict__ kl,
    const bf16_t* __restrict__ vt, const float* __restrict__ mf,
    bf16_t* __restrict__ ao)
{
    __shared__ float msk[SEQ];

    // XCD swizzle: the 8 blocks of one bh share an XCD (K/V L2 locality)
    const int g   = blockIdx.x;
    const int xcd = g & 7;
    const int s8  = g >> 3;
    const int bh  = ((s8 >> 3) << 3) + xcd;
    const int qb  = s8 & 7;
    const int b   = bh >> 4;
    const int hh  = bh & 15;

    const int t    = threadIdx.x;
    const int lane = t & 63;
    const int wave = t >> 6;
    const int col  = lane & 31;
    const int hf   = lane >> 5;

    // stage this batch's mask row (2048 floats) to LDS once
    {
        const float* mrow = mf + b * SEQ;
        #pragma unroll
        for (int i = 0; i < 2; ++i) {
            int idx = (t + i * 256) * 4;
            *(f32x4*)&msk[idx] = *(const f32x4*)(mrow + idx);
        }
    }
    __syncthreads();

    const int q0 = qb * 256 + wave * 64;   // tile0: q0.., tile1: q0+32..

    // Q fragments (B-operand): lane holds Q[q0+col][16c + 8*hf .. +7]
    const long qoff0 = ((long)(bh * SEQ + q0 + col)) * 64 + hf * 8;
    const long qoff1 = qoff0 + 32 * 64;
    bf16x8 qfh0[4], qfl0[4], qfh1[4], qfl1[4];
    #pragma unroll
    for (int c = 0; c < 4; ++c) {
        qfh0[c] = *(const bf16x8*)(qh + qoff0 + 16 * c);
        qfl0[c] = *(const bf16x8*)(ql + qoff0 + 16 * c);
        qfh1[c] = *(const bf16x8*)(qh + qoff1 + 16 * c);
        qfl1[c] = *(const bf16x8*)(ql + qoff1 + 16 * c);
    }

    f32x16 o00 = {}, o01 = {}, o10 = {}, o11 = {};
    float l0 = 0.f, l1 = 0.f;

    #pragma unroll 1
    for (int kt = 0; kt < SEQ; kt += 32) {
        // K fragments (A-operand), shared by both q-tiles
        const long koff = ((long)(bh * SEQ + kt + col)) * 64 + hf * 8;
        bf16x8 kfh[4], kfl[4];
        #pragma unroll
        for (int c = 0; c < 4; ++c) {
            kfh[c] = *(const bf16x8*)(kh + koff + 16 * c);
            kfl[c] = *(const bf16x8*)(kl + koff + 16 * c);
        }
        // V fragments (B-operand) from V^T, shared by both q-tiles
        const long vbase = ((long)(bh * 64)) * SEQ + kt + hf * 8;
        bf16x8 v00 = *(const bf16x8*)(vt + vbase + (long)col * SEQ);
        bf16x8 v01 = *(const bf16x8*)(vt + vbase + (long)col * SEQ + 16);
        bf16x8 v10 = *(const bf16x8*)(vt + vbase + (long)(col + 32) * SEQ);
        bf16x8 v11 = *(const bf16x8*)(vt + vbase + (long)(col + 32) * SEQ + 16);

        // mask multipliers from LDS (broadcast reads)
        f32x4 mm[4];
        #pragma unroll
        for (int gi = 0; gi < 4; ++gi)
            mm[gi] = *(const f32x4*)&msk[kt + 8 * gi + 4 * hf];

        // ---------------- tile 0 ----------------
        {
            f32x16 sA = {}, sB = {};
            #pragma unroll
            for (int c = 0; c < 4; ++c) {
                sA = mfma32(kfh[c], qfh0[c], sA);
                sB = mfma32(kfl[c], qfh0[c], sB);
                sB = mfma32(kfh[c], qfl0[c], sB);
            }
            float p[16];
            #pragma unroll
            for (int r = 0; r < 16; ++r) {
                float sv = floorf((sA[r] + sB[r]) * 0.125f);
                p[r] = __expf(sv) * mm[r >> 2][r & 3];
                l0 += p[r];
            }
            bf16x8 pa0, pa1;
            pack_p(p, pa0, pa1);
            o00 = mfma32(pa0, v00, o00);
            o00 = mfma32(pa1, v01, o00);
            o01 = mfma32(pa0, v10, o01);
            o01 = mfma32(pa1, v11, o01);
        }
        // ---------------- tile 1 ----------------
        {
            f32x16 sA = {}, sB = {};
            #pragma unroll
            for (int c = 0; c < 4; ++c) {
                sA = mfma32(kfh[c], qfh1[c], sA);
                sB = mfma32(kfl[c], qfh1[c], sB);
                sB = mfma32(kfh[c], qfl1[c], sB);
            }
            float p[16];
            #pragma unroll
            for (int r = 0; r < 16; ++r) {
                float sv = floorf((sA[r] + sB[r]) * 0.125f);
                p[r] = __expf(sv) * mm[r >> 2][r & 3];
                l1 += p[r];
            }
            bf16x8 pa0, pa1;
            pack_p(p, pa0, pa1);
            o10 = mfma32(pa0, v00, o10);
            o10 = mfma32(pa1, v01, o10);
            o11 = mfma32(pa0, v10, o11);
            o11 = mfma32(pa1, v11, o11);
        }
    }

    // epilogue, tile 0
    {
        float ltot = l0 + __shfl_xor(l0, 32);
        float linv = 1.0f / ltot;
        const long obase = ((long)(b * SEQ + q0)) * EMB + hh * 64;
        #pragma unroll
        for (int r = 0; r < 16; ++r) {
            int row = (r & 3) + ((r >> 2) << 3) + 4 * hf;
            float li = __shfl(linv, row);
            ao[obase + (long)row * EMB + col]      = (bf16_t)(o00[r] * li);
            ao[obase + (long)row * EMB + col + 32] = (bf16_t)(o01[r] * li);
        }
    }
    // epilogue, tile 1
    {
        float ltot = l1 + __shfl_xor(l1, 32);
        float linv = 1.0f / ltot;
        const long obase = ((long)(b * SEQ + q0 + 32)) * EMB + hh * 64;
        #pragma unroll
        for (int r = 0; r < 16; ++r) {
            int row = (r & 3) + ((r >> 2) << 3) + 4 * hf;
            float li = __shfl(linv, row);
            ao[obase + (long)row * EMB + col]      = (bf16_t)(o10[r] * li);
            ao[obase + (long)row * EMB + col + 32] = (bf16_t)(o11[r] * li);
        }
    }
}

// ---------------------------------------------------------------------------
// FC: out[8192,1024] = ao_bf16 @ Wfc_bf16^T + bfc.  Block = 128x128, 4 waves,
// wave = 64x64 (2x2 32x32 MFMA tiles).  Direct global fragment loads.
// ---------------------------------------------------------------------------
__global__ __launch_bounds__(256) void fc_kernel(
    const bf16_t* __restrict__ A, const bf16_t* __restrict__ W,
    const float* __restrict__ bias, float* __restrict__ out)
{
    const int lane = threadIdx.x & 63;
    const int wave = threadIdx.x >> 6;
    const int col  = lane & 31;
    const int hf   = lane >> 5;
    const int wm   = wave & 1;
    const int wn   = wave >> 1;
    const int m0   = blockIdx.x * 128 + wm * 64;
    const int n0   = blockIdx.y * 128 + wn * 64;

    f32x16 acc[2][2] = {};
    const bf16_t* arow0 = A + (long)(m0 + col) * EMB + hf * 8;
    const bf16_t* arow1 = A + (long)(m0 + 32 + col) * EMB + hf * 8;
    const bf16_t* brow0 = W + (long)(n0 + col) * EMB + hf * 8;
    const bf16_t* brow1 = W + (long)(n0 + 32 + col) * EMB + hf * 8;

    #pragma unroll 2
    for (int k0 = 0; k0 < EMB; k0 += 16) {
        bf16x8 a0 = *(const bf16x8*)(arow0 + k0);
        bf16x8 a1 = *(const bf16x8*)(arow1 + k0);
        bf16x8 b0 = *(const bf16x8*)(brow0 + k0);
        bf16x8 b1 = *(const bf16x8*)(brow1 + k0);
        acc[0][0] = mfma32(a0, b0, acc[0][0]);
        acc[0][1] = mfma32(a0, b1, acc[0][1]);
        acc[1][0] = mfma32(a1, b0, acc[1][0]);
        acc[1][1] = mfma32(a1, b1, acc[1][1]);
    }

    const float b0v = bias[n0 + col];
    const float b1v = bias[n0 + 32 + col];
    #pragma unroll
    for (int mt = 0; mt < 2; ++mt) {
        #pragma unroll
        for (int r = 0; r < 16; ++r) {
            int mrow = m0 + mt * 32 + (r & 3) + ((r >> 2) << 3) + 4 * hf;
            out[(long)mrow * EMB + n0 + col]      = acc[mt][0][r] + b0v;
            out[(long)mrow * EMB + n0 + 32 + col] = acc[mt][1][r] + b1v;
        }
    }
}

// ---------------------------------------------------------------------------
extern "C" void kernel_launch(void* const* d_in, const int* in_sizes, int n_in,
                              void* d_out, int out_size, void* d_ws, size_t ws_size,
                              hipStream_t stream)
{
    const float* q    = (const float*)d_in[0];
    const float* k    = (const float*)d_in[1];
    const float* v    = (const float*)d_in[2];
    const int*   mask = (const int*)  d_in[3];
    const float* Wq   = (const float*)d_in[4];
    const float* bq   = (const float*)d_in[5];
    const float* Wk   = (const float*)d_in[6];
    const float* bk   = (const float*)d_in[7];
    const float* Wv   = (const float*)d_in[8];
    const float* bv   = (const float*)d_in[9];
    const float* Wfc  = (const float*)d_in[10];
    const float* bfc  = (const float*)d_in[11];
    float* out = (float*)d_out;

    const long NP = (long)BATCH * HEADS * SEQ * 64;   // 8,388,608 elems
    bf16_t* qhp = (bf16_t*)d_ws;
    bf16_t* qlp = qhp + NP;
    bf16_t* khp = qlp + NP;
    bf16_t* klp = khp + NP;
    bf16_t* vtp = klp + NP;
    bf16_t* aop = vtp + NP;                 // [B*SEQ][EMB] bf16
    bf16_t* wbp = aop + (long)BATCH * SEQ * EMB;   // [EMB][EMB] bf16
    float*  mfp = (float*)(wbp + (long)EMB * EMB);

    maskf_kernel<<<(BATCH * SEQ + 255) / 256, 256, 0, stream>>>(mask, mfp, BATCH * SEQ);
    wconv_kernel<<<(EMB * EMB / 4) / 256, 256, 0, stream>>>(Wfc, wbp, EMB * EMB);

    dim3 gP(2048, 3);
    proj_kernel<<<gP, 256, 0, stream>>>(q, k, v, Wq, bq, Wk, bk, Wv, bv,
                                        qhp, qlp, khp, klp, vtp);

    attn_kernel<<<512, 256, 0, stream>>>(qhp, qlp, khp, klp, vtp, mfp, aop);

    dim3 gC(64, 8);
    fc_kernel<<<gC, 256, 0, stream>>>(aop, wbp, bfc, out);
}